// Round 6
// baseline (614.682 us; speedup 1.0000x reference)
//
#include <hip/hip_runtime.h>
#include <hip/hip_bf16.h>

// B=8, S=2048, H=1024 — split-bf16 (fp32-emulation) MFMA pipeline.
//   x  -> x_hi/x_lo bf16; W -> Wt_hi/lo (transposed)
//   xw     = x @ W        3-pass split-bf16 MFMA -> xw_hi/lo   [2-PHASE 256², BK=32]
//   scores = xw @ x^T     3-pass split-bf16 MFMA -> attn fp32  [2-PHASE 256², BK=32]
//   attn   = softmax      in place + bf16 copy
//   ctx    = attn @ x     1-pass bf16 MFMA (NT via xT)         [2-PHASE 256², BK=64]
//
// Round 10: pass-major MFMA clusters + deferred-lo read overlap.
// Each 48-MFMA cluster becomes [16 hh][16 hl][16 lh] (per-acc order preserved
// -> bit-identical). a_h and b_l are dead after the hl pass, so their
// NEXT-tile ds_reads issue between hl and lh — 12 of 24 per-wave reads per
// K-tile now drain on the LDS port while the lh MFMAs occupy the matrix pipe
// (issue-early / consume-next-window; LDS data already vmcnt-retired and
// barrier-visible; reg-WAR is the proven after-last-consumer pattern).
// Residual post-cluster reads: a_l / b_h only. ctx analog: [ks0][ks1] with
// slot0 reads mid-cluster. Staging schedule, vmcnt(8/4), barriers unchanged
// from the verified round-9 structure.

#define BB 8
#define SS 2048
#define HH 1024

typedef __attribute__((ext_vector_type(8))) short bf16x8;
typedef __attribute__((ext_vector_type(4))) float f32x4;

__device__ __forceinline__ void async_load16(const void* gsrc, void* ldst) {
    typedef const unsigned int __attribute__((address_space(1)))* gp_t;
    typedef unsigned int __attribute__((address_space(3)))* lp_t;
    __builtin_amdgcn_global_load_lds((gp_t)gsrc, (lp_t)ldst, 16, 0, 0);
}

__device__ __forceinline__ unsigned short f2b(float f) {
    __hip_bfloat16 h = __float2bfloat16(f);
    return *(unsigned short*)&h;
}
__device__ __forceinline__ float b2f(unsigned short u) {
    __hip_bfloat16 h = *(__hip_bfloat16*)&u;
    return __bfloat162float(h);
}

// ----------------------------------------------------------- split x -> hi/lo bf16
__global__ __launch_bounds__(256) void split_x(const float* __restrict__ X,
                                               unsigned short* __restrict__ Xh,
                                               unsigned short* __restrict__ Xl) {
    const size_t i = ((size_t)blockIdx.x * 256 + threadIdx.x) * 8;
    float4 a = *(const float4*)(X + i);
    float4 b = *(const float4*)(X + i + 4);
    ushort4 h0, h1, l0, l1;
    float v, hf;
    v = a.x; h0.x = f2b(v); hf = b2f(h0.x); l0.x = f2b(v - hf);
    v = a.y; h0.y = f2b(v); hf = b2f(h0.y); l0.y = f2b(v - hf);
    v = a.z; h0.z = f2b(v); hf = b2f(h0.z); l0.z = f2b(v - hf);
    v = a.w; h0.w = f2b(v); hf = b2f(h0.w); l0.w = f2b(v - hf);
    v = b.x; h1.x = f2b(v); hf = b2f(h1.x); l1.x = f2b(v - hf);
    v = b.y; h1.y = f2b(v); hf = b2f(h1.y); l1.y = f2b(v - hf);
    v = b.z; h1.z = f2b(v); hf = b2f(h1.z); l1.z = f2b(v - hf);
    v = b.w; h1.w = f2b(v); hf = b2f(h1.w); l1.w = f2b(v - hf);
    *(ushort4*)(Xh + i) = h0; *(ushort4*)(Xh + i + 4) = h1;
    *(ushort4*)(Xl + i) = l0; *(ushort4*)(Xl + i + 4) = l1;
}

// ------------------------------------- W [k][n] -> Wt hi/lo [n][k] (bf16 split, transpose)
__global__ __launch_bounds__(256) void split_wT(const float* __restrict__ W,
                                                unsigned short* __restrict__ Th,
                                                unsigned short* __restrict__ Tl) {
    const int k0 = blockIdx.y * 64, n0 = blockIdx.x * 64;
    __shared__ float tile[64][65];
#pragma unroll
    for (int q = 0; q < 16; q++) {
        int idx = q * 256 + threadIdx.x;
        int r = idx >> 6, c = idx & 63;
        tile[r][c] = W[(size_t)(k0 + r) * HH + n0 + c];
    }
    __syncthreads();
#pragma unroll
    for (int q = 0; q < 16; q++) {
        int idx = q * 256 + threadIdx.x;
        int r = idx >> 6, c = idx & 63;
        float v = tile[c][r];
        unsigned short h = f2b(v);
        Th[(size_t)(n0 + r) * HH + k0 + c] = h;
        Tl[(size_t)(n0 + r) * HH + k0 + c] = f2b(v - b2f(h));
    }
}

// ---- helper macros for the shared split-bf16 body ----
#define STG_A(mh, kt, buf) do { \
        const size_t o_ = aOff + (size_t)(mh) * 64 * HH + (size_t)(kt) * 32; \
        async_load16(A_h + o_, (char*)lds + ((buf) * 32768 + (mh) * 4096) * 2 + wt16); \
        async_load16(A_l + o_, (char*)lds + ((buf) * 32768 + 8192 + (mh) * 4096) * 2 + wt16); \
    } while (0)
#define STG_B(nh, kt, buf) do { \
        const size_t o_ = bOff + (size_t)(nh) * 32 * HH + (size_t)(kt) * 32; \
        async_load16(B_h + o_, (char*)lds + ((buf) * 32768 + 16384 + (nh) * 4096) * 2 + wt16); \
        async_load16(B_l + o_, (char*)lds + ((buf) * 32768 + 24576 + (nh) * 4096) * 2 + wt16); \
    } while (0)
#define RD_A_H(mh, buf) do { \
        const int s0_ = (buf) * 32768 + ((mh) * 128 + wy * 64 + m16) * 32 + cs * 8; \
        _Pragma("unroll") for (int mi = 0; mi < 4; ++mi) \
            a_h[mi] = *(const bf16x8*)&lds[s0_ + mi * 512]; \
    } while (0)
#define RD_A_L(mh, buf) do { \
        const int s0_ = (buf) * 32768 + ((mh) * 128 + wy * 64 + m16) * 32 + cs * 8; \
        _Pragma("unroll") for (int mi = 0; mi < 4; ++mi) \
            a_l[mi] = *(const bf16x8*)&lds[8192 + s0_ + mi * 512]; \
    } while (0)
#define RD_B_H(nh, buf) do { \
        const int s0_ = (buf) * 32768 + ((nh) * 128 + wx * 32 + m16) * 32 + cs * 8; \
        _Pragma("unroll") for (int nj = 0; nj < 2; ++nj) \
            b_h[nh][nj] = *(const bf16x8*)&lds[16384 + s0_ + nj * 512]; \
    } while (0)
#define RD_B_L(nh, buf) do { \
        const int s0_ = (buf) * 32768 + ((nh) * 128 + wx * 32 + m16) * 32 + cs * 8; \
        _Pragma("unroll") for (int nj = 0; nj < 2; ++nj) \
            b_l[nh][nj] = *(const bf16x8*)&lds[24576 + s0_ + nj * 512]; \
    } while (0)
// pass-major MFMA passes (per-acc order hh -> hl -> lh preserved = bit-identical)
#define PASS_HH(mh) \
        _Pragma("unroll") for (int mi = 0; mi < 4; ++mi) \
        _Pragma("unroll") for (int nh = 0; nh < 2; ++nh) \
        _Pragma("unroll") for (int nj = 0; nj < 2; ++nj) \
            acc[mh][mi][nh][nj] = __builtin_amdgcn_mfma_f32_16x16x32_bf16(a_h[mi], b_h[nh][nj], acc[mh][mi][nh][nj], 0, 0, 0);
#define PASS_HL(mh) \
        _Pragma("unroll") for (int mi = 0; mi < 4; ++mi) \
        _Pragma("unroll") for (int nh = 0; nh < 2; ++nh) \
        _Pragma("unroll") for (int nj = 0; nj < 2; ++nj) \
            acc[mh][mi][nh][nj] = __builtin_amdgcn_mfma_f32_16x16x32_bf16(a_h[mi], b_l[nh][nj], acc[mh][mi][nh][nj], 0, 0, 0);
#define PASS_LH(mh) \
        _Pragma("unroll") for (int mi = 0; mi < 4; ++mi) \
        _Pragma("unroll") for (int nh = 0; nh < 2; ++nh) \
        _Pragma("unroll") for (int nj = 0; nj < 2; ++nj) \
            acc[mh][mi][nh][nj] = __builtin_amdgcn_mfma_f32_16x16x32_bf16(a_l[mi], b_h[nh][nj], acc[mh][mi][nh][nj], 0, 0, 0);

// Shared 2-phase split-bf16 GEMM body (NT, 256² tile, BK=32, 2M x 4N waves).
//   ph0 (mh0): STG_A(kt+1->bufn) vmcnt(8) bar | hh hl | RD_A_H(1) | lh | RD_A_L(1) | bar
//   ph1 (mh1): STG_B(kt+2->bufc) vmcnt(4) bar | hh hl | RD_B_L(01)+RD_A_H(0) | lh | RD_B_H(01)+RD_A_L(0) | bar
#define SPLIT3_2PH_BODY(A_h, A_l, B_h, B_l)                                         \
    __shared__ __align__(16) unsigned short lds[65536];                             \
    const int tid = threadIdx.x;                                                    \
    const int wave = tid >> 6, lane = tid & 63;                                     \
    const int m16 = lane & 15, quad = lane >> 4;                                    \
    const int wy = wave >> 2, wx = wave & 3;                                        \
    const int rP = tid >> 2;                                                        \
    const int kq = (tid & 3) ^ ((rP >> 1) & 3);                                     \
    const int cs = quad ^ ((m16 >> 1) & 3);                                         \
    const int wt16 = wave * 1024;                                                   \
    const int rowA_off = (rP & 63) + ((rP >> 6) << 7);                              \
    const int rowB_off = ((rP >> 5) << 6) + (rP & 31);                              \
    const size_t aOff = (size_t)(i0 + rowA_off) * HH + kq * 8;                      \
    const size_t bOff = (size_t)(j0 + rowB_off) * HH + kq * 8;                      \
    f32x4 acc[2][4][2][2] = {};                                                     \
    bf16x8 a_h[4], a_l[4], b_h[2][2], b_l[2][2];                                    \
    STG_A(0, 0, 0); STG_A(1, 0, 0);                                                 \
    STG_B(0, 0, 0); STG_B(1, 0, 0);                                                 \
    STG_B(0, 1, 1); STG_B(1, 1, 1);                                                 \
    asm volatile("s_waitcnt vmcnt(4)" ::: "memory");                                \
    __builtin_amdgcn_s_barrier();                                                   \
    RD_A_H(0, 0); RD_A_L(0, 0);                                                     \
    RD_B_H(0, 0); RD_B_L(0, 0); RD_B_H(1, 0); RD_B_L(1, 0);                         \
    for (int kt = 0; kt < 32; ++kt) {                                               \
        const int bufc = kt & 1, bufn = bufc ^ 1;                                   \
        const int ktA = kt < 31 ? kt + 1 : 31;                                      \
        const int ktB = kt < 30 ? kt + 2 : 31;                                      \
        /* ---- ph0 (mh0) */                                                        \
        STG_A(0, ktA, bufn);                                                        \
        STG_A(1, ktA, bufn);                                                        \
        asm volatile("s_waitcnt vmcnt(8)" ::: "memory");                            \
        __builtin_amdgcn_s_barrier();                                               \
        __builtin_amdgcn_sched_barrier(0);                                          \
        __builtin_amdgcn_s_setprio(1);                                              \
        PASS_HH(0)                                                                  \
        PASS_HL(0)                                                                  \
        __builtin_amdgcn_sched_barrier(0);                                          \
        RD_A_H(1, bufc);                                                            \
        __builtin_amdgcn_sched_barrier(0);                                          \
        PASS_LH(0)                                                                  \
        __builtin_amdgcn_s_setprio(0);                                              \
        __builtin_amdgcn_sched_barrier(0);                                          \
        RD_A_L(1, bufc);                                                            \
        __builtin_amdgcn_s_barrier();                                               \
        /* ---- ph1 (mh1) */                                                        \
        STG_B(0, ktB, bufc);                                                        \
        STG_B(1, ktB, bufc);                                                        \
        asm volatile("s_waitcnt vmcnt(4)" ::: "memory");                            \
        __builtin_amdgcn_s_barrier();                                               \
        __builtin_amdgcn_sched_barrier(0);                                          \
        __builtin_amdgcn_s_setprio(1);                                              \
        PASS_HH(1)                                                                  \
        PASS_HL(1)                                                                  \
        __builtin_amdgcn_sched_barrier(0);                                          \
        RD_B_L(0, bufn); RD_B_L(1, bufn); RD_A_H(0, bufn);                          \
        __builtin_amdgcn_sched_barrier(0);                                          \
        PASS_LH(1)                                                                  \
        __builtin_amdgcn_s_setprio(0);                                              \
        __builtin_amdgcn_sched_barrier(0);                                          \
        RD_B_H(0, bufn); RD_B_H(1, bufn); RD_A_L(0, bufn);                          \
        __builtin_amdgcn_s_barrier();                                               \
    }

// ---------------- xw = x @ Wt^T (NT), 3-pass split-bf16, 2-phase 256² BK=32, bf16 hi/lo out
__global__ __launch_bounds__(512, 2) void gemm_xw3_8p(const unsigned short* __restrict__ Ah,
                                                      const unsigned short* __restrict__ Al,
                                                      const unsigned short* __restrict__ Bh,
                                                      const unsigned short* __restrict__ Bl,
                                                      unsigned short* __restrict__ Ch,
                                                      unsigned short* __restrict__ Cl) {
    const int b = blockIdx.z;
    const int i0 = blockIdx.y * 256, j0 = blockIdx.x * 256;
    const unsigned short* A_h = Ah + (size_t)b * SS * HH;
    const unsigned short* A_l = Al + (size_t)b * SS * HH;
    const unsigned short* B_h = Bh;   // Wt: no batch offset
    const unsigned short* B_l = Bl;

    SPLIT3_2PH_BODY(A_h, A_l, B_h, B_l)

    unsigned short* ChB = Ch + (size_t)b * SS * HH;
    unsigned short* ClB = Cl + (size_t)b * SS * HH;
#pragma unroll
    for (int mh = 0; mh < 2; ++mh)
#pragma unroll
        for (int mi = 0; mi < 4; ++mi)
#pragma unroll
            for (int nh = 0; nh < 2; ++nh)
#pragma unroll
                for (int nj = 0; nj < 2; ++nj) {
                    const int row = i0 + wy * 128 + mh * 64 + mi * 16 + quad * 4;
                    const int col = j0 + wx * 64 + nh * 32 + nj * 16 + m16;
#pragma unroll
                    for (int reg = 0; reg < 4; ++reg) {
                        float v = acc[mh][mi][nh][nj][reg];
                        unsigned short h = f2b(v);
                        ChB[(size_t)(row + reg) * HH + col] = h;
                        ClB[(size_t)(row + reg) * HH + col] = f2b(v - b2f(h));
                    }
                }
}

// ---------------- scores = xw @ x^T (NT), 3-pass split-bf16 MFMA, fp32 out
__global__ __launch_bounds__(512, 2) void gemm_sc3_8p(const unsigned short* __restrict__ Ah,
                                                      const unsigned short* __restrict__ Al,
                                                      const unsigned short* __restrict__ Bh,
                                                      const unsigned short* __restrict__ Bl,
                                                      float* __restrict__ SC) {
    const int b = blockIdx.z;
    const int i0 = blockIdx.y * 256, j0 = blockIdx.x * 256;
    const unsigned short* A_h = Ah + (size_t)b * SS * HH;
    const unsigned short* A_l = Al + (size_t)b * SS * HH;
    const unsigned short* B_h = Bh + (size_t)b * SS * HH;
    const unsigned short* B_l = Bl + (size_t)b * SS * HH;

    SPLIT3_2PH_BODY(A_h, A_l, B_h, B_l)

    float* Cb = SC + (size_t)b * SS * SS;
#pragma unroll
    for (int mh = 0; mh < 2; ++mh)
#pragma unroll
        for (int mi = 0; mi < 4; ++mi)
#pragma unroll
            for (int nh = 0; nh < 2; ++nh)
#pragma unroll
                for (int nj = 0; nj < 2; ++nj) {
                    const int row = i0 + wy * 128 + mh * 64 + mi * 16 + quad * 4;
                    const int col = j0 + wx * 64 + nh * 32 + nj * 16 + m16;
#pragma unroll
                    for (int reg = 0; reg < 4; ++reg)
                        Cb[(size_t)(row + reg) * SS + col] = acc[mh][mi][nh][nj][reg];
                }
}

#undef STG_A
#undef STG_B
#undef RD_A_H
#undef RD_A_L
#undef RD_B_H
#undef RD_B_L
#undef PASS_HH
#undef PASS_HL
#undef PASS_LH
#undef SPLIT3_2PH_BODY

// --------------------------- softmax in place (fp32) + bf16 copy for the MFMA ctx GEMM
__global__ __launch_bounds__(256) void softmax_rows(float* __restrict__ P,
                                                    unsigned short* __restrict__ Pb) {
    const size_t row = blockIdx.x;
    float4* p4 = (float4*)(P + row * SS);
    const int tid = threadIdx.x;
    float4 v0 = p4[tid], v1 = p4[tid + 256];
    float m = fmaxf(fmaxf(fmaxf(v0.x, v0.y), fmaxf(v0.z, v0.w)),
                    fmaxf(fmaxf(v1.x, v1.y), fmaxf(v1.z, v1.w)));
#pragma unroll
    for (int off = 32; off; off >>= 1) m = fmaxf(m, __shfl_xor(m, off));
    __shared__ float red[4];
    const int wid = tid >> 6, lane = tid & 63;
    if (lane == 0) red[wid] = m;
    __syncthreads();
    m = fmaxf(fmaxf(red[0], red[1]), fmaxf(red[2], red[3]));
    v0.x = __expf(v0.x - m); v0.y = __expf(v0.y - m);
    v0.z = __expf(v0.z - m); v0.w = __expf(v0.w - m);
    v1.x = __expf(v1.x - m); v1.y = __expf(v1.y - m);
    v1.z = __expf(v1.z - m); v1.w = __expf(v1.w - m);
    float s = v0.x + v0.y + v0.z + v0.w + v1.x + v1.y + v1.z + v1.w;
#pragma unroll
    for (int off = 32; off; off >>= 1) s += __shfl_xor(s, off);
    __syncthreads();
    if (lane == 0) red[wid] = s;
    __syncthreads();
    s = red[0] + red[1] + red[2] + red[3];
    const float inv = 1.0f / s;
    v0.x *= inv; v0.y *= inv; v0.z *= inv; v0.w *= inv;
    v1.x *= inv; v1.y *= inv; v1.z *= inv; v1.w *= inv;
    p4[tid] = v0;
    p4[tid + 256] = v1;
    ushort4* b4 = (ushort4*)(Pb + row * SS);
    ushort4 u0 = { f2b(v0.x), f2b(v0.y), f2b(v0.z), f2b(v0.w) };
    ushort4 u1 = { f2b(v1.x), f2b(v1.y), f2b(v1.z), f2b(v1.w) };
    b4[tid] = u0;
    b4[tid + 256] = u1;
}

// --------------------------------- x [B,S,H] fp32 -> xT [B,H,S] bf16 (for NT ctx GEMM)
__global__ __launch_bounds__(256) void transpose_cvt(const float* __restrict__ X,
                                                     unsigned short* __restrict__ XT) {
    const int b = blockIdx.z;
    const int t0 = blockIdx.y * 64;
    const int h0 = blockIdx.x * 64;
    __shared__ float tile[64][65];
    const float* Xb = X + (size_t)b * SS * HH;
    unsigned short* Tb = XT + (size_t)b * HH * SS;
#pragma unroll
    for (int q = 0; q < 16; q++) {
        int idx = q * 256 + threadIdx.x;
        int r = idx >> 6, c = idx & 63;
        tile[r][c] = Xb[(size_t)(t0 + r) * HH + h0 + c];
    }
    __syncthreads();
#pragma unroll
    for (int q = 0; q < 16; q++) {
        int idx = q * 256 + threadIdx.x;
        int r = idx >> 6, c = idx & 63;
        Tb[(size_t)(h0 + r) * SS + t0 + c] = f2b(tile[c][r]);
    }
}

// ----------------- ctx = attn @ x (NT bf16 MFMA), 2-phase 256² tile, BK=64, 1-pass
// Slot-major clusters [ks0][ks1]; slot0 next-reads mid-cluster (dead after ks0 pass).
__global__ __launch_bounds__(512, 2) void gemm_ctx_8p(const unsigned short* __restrict__ Ab,
                                                      const unsigned short* __restrict__ Bt,
                                                      float* __restrict__ C) {
    const int b = blockIdx.z;
    const int i0 = blockIdx.y * 256, n0 = blockIdx.x * 256;
    const unsigned short* A = Ab + (size_t)b * SS * SS;
    const unsigned short* B = Bt + (size_t)b * HH * SS;

    __shared__ __align__(16) unsigned short lds[65536];   // 128 KB

    const int tid = threadIdx.x;
    const int wave = tid >> 6, lane = tid & 63;
    const int m16 = lane & 15, quad = lane >> 4;
    const int m7 = m16 & 7;
    const int wy = wave >> 2, wx = wave & 3;
    const int rA8 = tid >> 3;
    const int c8 = (tid & 7) ^ (rA8 & 7);
    const int wt16 = wave * 1024;
    const int sl0 = (quad ^ m7) * 8;          // ushort offset, ks=0 slot
    const int sl1 = ((quad + 4) ^ m7) * 8;    // ks=1 slot

    const size_t aSrc = (size_t)(i0 + rA8) * SS + c8 * 8;
    const size_t bSrc = (size_t)(n0 + ((rA8 >> 5) << 6) + (rA8 & 31)) * SS + c8 * 8;

    f32x4 acc[2][4][2][2] = {};               // [mh][mi][nh][nj]
    bf16x8 a[4][2], bb[2][2][2];              // a[mi][ks], bb[nh][nj][ks]

#define CSTG_A(mh, h, kt, buf) \
    async_load16(A + aSrc + (size_t)((mh) * 64 + (h) * 128) * SS + (size_t)(kt) * 64, \
                 (char*)lds + (buf) * 65536 + (mh) * 16384 + (h) * 8192 + wt16)
#define CSTG_B(nh, h, kt, buf) \
    async_load16(B + bSrc + (size_t)((h) * 128 + (nh) * 32) * SS + (size_t)(kt) * 64, \
                 (char*)lds + (buf) * 65536 + 32768 + (nh) * 16384 + (h) * 8192 + wt16)
#define CRD_A_S0(mh, buf) do { \
        const int r0_ = (buf) * 32768 + ((mh) * 128 + wy * 64 + m16) * 64; \
        _Pragma("unroll") for (int mi = 0; mi < 4; ++mi) \
            a[mi][0] = *(const bf16x8*)&lds[r0_ + mi * 1024 + sl0]; \
    } while (0)
#define CRD_A_S1(mh, buf) do { \
        const int r0_ = (buf) * 32768 + ((mh) * 128 + wy * 64 + m16) * 64; \
        _Pragma("unroll") for (int mi = 0; mi < 4; ++mi) \
            a[mi][1] = *(const bf16x8*)&lds[r0_ + mi * 1024 + sl1]; \
    } while (0)
#define CRD_B_S0(nh, buf) do { \
        const int r0_ = (buf) * 32768 + 16384 + (nh) * 8192 + (wx * 32 + m16) * 64; \
        _Pragma("unroll") for (int nj = 0; nj < 2; ++nj) \
            bb[nh][nj][0] = *(const bf16x8*)&lds[r0_ + nj * 1024 + sl0]; \
    } while (0)
#define CRD_B_S1(nh, buf) do { \
        const int r0_ = (buf) * 32768 + 16384 + (nh) * 8192 + (wx * 32 + m16) * 64; \
        _Pragma("unroll") for (int nj = 0; nj < 2; ++nj) \
            bb[nh][nj][1] = *(const bf16x8*)&lds[r0_ + nj * 1024 + sl1]; \
    } while (0)
#define CPASS0(mh) \
        _Pragma("unroll") for (int mi = 0; mi < 4; ++mi) \
        _Pragma("unroll") for (int nh = 0; nh < 2; ++nh) \
        _Pragma("unroll") for (int nj = 0; nj < 2; ++nj) \
            acc[mh][mi][nh][nj] = __builtin_amdgcn_mfma_f32_16x16x32_bf16(a[mi][0], bb[nh][nj][0], acc[mh][mi][nh][nj], 0, 0, 0);
#define CPASS1(mh) \
        _Pragma("unroll") for (int mi = 0; mi < 4; ++mi) \
        _Pragma("unroll") for (int nh = 0; nh < 2; ++nh) \
        _Pragma("unroll") for (int nj = 0; nj < 2; ++nj) \
            acc[mh][mi][nh][nj] = __builtin_amdgcn_mfma_f32_16x16x32_bf16(a[mi][1], bb[nh][nj][1], acc[mh][mi][nh][nj], 0, 0, 0);

    CSTG_A(0, 0, 0, 0); CSTG_A(0, 1, 0, 0);
    CSTG_A(1, 0, 0, 0); CSTG_A(1, 1, 0, 0);
    CSTG_B(0, 0, 0, 0); CSTG_B(0, 1, 0, 0);
    CSTG_B(1, 0, 0, 0); CSTG_B(1, 1, 0, 0);
    CSTG_B(0, 0, 1, 1); CSTG_B(0, 1, 1, 1);
    CSTG_B(1, 0, 1, 1); CSTG_B(1, 1, 1, 1);
    asm volatile("s_waitcnt vmcnt(4)" ::: "memory");
    __builtin_amdgcn_s_barrier();
    CRD_A_S0(0, 0); CRD_A_S1(0, 0);
    CRD_B_S0(0, 0); CRD_B_S1(0, 0); CRD_B_S0(1, 0); CRD_B_S1(1, 0);

    for (int kt = 0; kt < 32; ++kt) {
        const int bufc = kt & 1, bufn = bufc ^ 1;
        const int ktA = kt < 31 ? kt + 1 : 31;
        const int ktB = kt < 30 ? kt + 2 : 31;
        // ---- ph0 (mh0)
        CSTG_A(0, 0, ktA, bufn); CSTG_A(0, 1, ktA, bufn);
        CSTG_A(1, 0, ktA, bufn); CSTG_A(1, 1, ktA, bufn);
        asm volatile("s_waitcnt vmcnt(8)" ::: "memory");
        __builtin_amdgcn_s_barrier();
        __builtin_amdgcn_sched_barrier(0);
        __builtin_amdgcn_s_setprio(1);
        CPASS0(0)
        __builtin_amdgcn_sched_barrier(0);
        CRD_A_S0(1, bufc);
        __builtin_amdgcn_sched_barrier(0);
        CPASS1(0)
        __builtin_amdgcn_s_setprio(0);
        __builtin_amdgcn_sched_barrier(0);
        CRD_A_S1(1, bufc);
        __builtin_amdgcn_s_barrier();
        // ---- ph1 (mh1)
        CSTG_B(0, 0, ktB, bufc); CSTG_B(0, 1, ktB, bufc);
        CSTG_B(1, 0, ktB, bufc); CSTG_B(1, 1, ktB, bufc);
        asm volatile("s_waitcnt vmcnt(4)" ::: "memory");
        __builtin_amdgcn_s_barrier();
        __builtin_amdgcn_sched_barrier(0);
        __builtin_amdgcn_s_setprio(1);
        CPASS0(1)
        __builtin_amdgcn_sched_barrier(0);
        CRD_B_S0(0, bufn); CRD_B_S0(1, bufn); CRD_A_S0(0, bufn);
        __builtin_amdgcn_sched_barrier(0);
        CPASS1(1)
        __builtin_amdgcn_s_setprio(0);
        __builtin_amdgcn_sched_barrier(0);
        CRD_B_S1(0, bufn); CRD_B_S1(1, bufn); CRD_A_S1(0, bufn);
        __builtin_amdgcn_s_barrier();
    }

    float* Cb = C + (size_t)b * SS * HH;
#pragma unroll
    for (int mh = 0; mh < 2; ++mh)
#pragma unroll
        for (int mi = 0; mi < 4; ++mi)
#pragma unroll
            for (int nh = 0; nh < 2; ++nh)
#pragma unroll
                for (int nj = 0; nj < 2; ++nj) {
                    const int row = i0 + wy * 128 + mh * 64 + mi * 16 + quad * 4;
                    const int col = n0 + wx * 64 + nh * 32 + nj * 16 + m16;
#pragma unroll
                    for (int reg = 0; reg < 4; ++reg)
                        Cb[(size_t)(row + reg) * HH + col] = acc[mh][mi][nh][nj][reg];
                }
#undef CSTG_A
#undef CSTG_B
#undef CRD_A_S0
#undef CRD_A_S1
#undef CRD_B_S0
#undef CRD_B_S1
#undef CPASS0
#undef CPASS1
}

extern "C" void kernel_launch(void* const* d_in, const int* in_sizes, int n_in,
                              void* d_out, int out_size, void* d_ws, size_t ws_size,
                              hipStream_t stream) {
    const float* X = (const float*)d_in[0];   // [8,2048,1024]
    const float* W = (const float*)d_in[1];   // [1024,1024]
    float* ctx  = (float*)d_out;                            // [8,2048,1024]
    float* attn = ctx + (size_t)BB * SS * HH;               // [8,2048,2048]

    char* ws = (char*)d_ws;
    unsigned short* x_hi  = (unsigned short*)ws;                         // [0,32M)
    unsigned short* x_lo  = (unsigned short*)(ws + ((size_t)32 << 20));  // [32,64M)
    unsigned short* wt_hi = (unsigned short*)(ws + ((size_t)64 << 20));  // [64,66M)
    unsigned short* wt_lo = (unsigned short*)(ws + ((size_t)66 << 20));  // [66,68M)
    unsigned short* xT     = x_hi;                                       // after scores
    unsigned short* attn_b = x_lo;                                       // after scores

    unsigned short* xw_hi = (unsigned short*)d_out;   // dead ctx region until final GEMM
    unsigned short* xw_lo = xw_hi + (size_t)BB * SS * HH;

    dim3 blk(256);
    split_x <<<dim3(BB * SS * HH / (8 * 256)), blk, 0, stream>>>(X, x_hi, x_lo);
    split_wT<<<dim3(HH / 64, HH / 64), blk, 0, stream>>>(W, wt_hi, wt_lo);
    gemm_xw3_8p<<<dim3(HH / 256, SS / 256, BB), dim3(512), 0, stream>>>(x_hi, x_lo, wt_hi, wt_lo, xw_hi, xw_lo);
    gemm_sc3_8p<<<dim3(SS / 256, SS / 256, BB), dim3(512), 0, stream>>>(xw_hi, xw_lo, x_hi, x_lo, attn);
    transpose_cvt<<<dim3(HH / 64, SS / 64, BB), blk, 0, stream>>>(X, xT);
    softmax_rows <<<dim3(BB * SS), blk, 0, stream>>>(attn, attn_b);
    gemm_ctx_8p<<<dim3(HH / 256, SS / 256, BB), dim3(512), 0, stream>>>(attn_b, xT, ctx);
}

// Round 9
// 596.977 us; speedup vs baseline: 1.0297x; 1.0297x over previous
//
#include <hip/hip_runtime.h>
#include <hip/hip_bf16.h>

// B=8, S=2048, H=1024 — split-bf16 (fp32-emulation) MFMA pipeline.
//   x  -> x_hi/x_lo bf16; W -> Wt_hi/lo (transposed)
//   xw     = x @ W        3-pass split-bf16 MFMA -> xw_hi/lo   [2-PHASE 256², BK=32]
//   scores = xw @ x^T     3-pass split-bf16 MFMA -> attn fp32  [2-PHASE 256², BK=32]
//   attn   = softmax      in place + bf16 copy (2 rows/block, NT fp32 stores)
//   ctx    = attn @ x     1-pass bf16 MFMA (NT via xT)         [2-PHASE 256², BK=64]
//
// Round 13 (= round 11 with the nontemporal-store compile fix):
// __builtin_nontemporal_store requires a scalar/ext_vector pointer — HIP's
// float4 struct is invalid. Softmax now stores via the ext_vector f32x4
// typedef (same bytes, same addresses). Payload otherwise identical to r11:
// XCD-chunked bijective block swizzle (T1/m204) on all three GEMMs, softmax
// 2 rows/block, ctx fp32 output nontemporal. Numerics bit-identical.

#define BB 8
#define SS 2048
#define HH 1024

typedef __attribute__((ext_vector_type(8))) short bf16x8;
typedef __attribute__((ext_vector_type(4))) float f32x4;

__device__ __forceinline__ void async_load16(const void* gsrc, void* ldst) {
    typedef const unsigned int __attribute__((address_space(1)))* gp_t;
    typedef unsigned int __attribute__((address_space(3)))* lp_t;
    __builtin_amdgcn_global_load_lds((gp_t)gsrc, (lp_t)ldst, 16, 0, 0);
}

__device__ __forceinline__ unsigned short f2b(float f) {
    __hip_bfloat16 h = __float2bfloat16(f);
    return *(unsigned short*)&h;
}
__device__ __forceinline__ float b2f(unsigned short u) {
    __hip_bfloat16 h = *(__hip_bfloat16*)&u;
    return __bfloat162float(h);
}

// XCD-chunked bijective tile swizzle: hw linear L -> tile T = (L%8)*(nwg/8) + L/8.
// All blocks on XCD k (L%8==k) process one contiguous tile chunk (= one batch):
// consecutive tiles share A-panels through that XCD's private L2.
__device__ __forceinline__ void swz_tile(int nx, int ny, int& tx, int& ty, int& tz) {
    const int L = blockIdx.x + nx * (blockIdx.y + ny * blockIdx.z);
    const int cpx = (nx * ny * BB) >> 3;
    const int T = (L & 7) * cpx + (L >> 3);
    tx = T % nx;
    const int t2 = T / nx;
    ty = t2 % ny;
    tz = t2 / ny;
}

// ----------------------------------------------------------- split x -> hi/lo bf16
__global__ __launch_bounds__(256) void split_x(const float* __restrict__ X,
                                               unsigned short* __restrict__ Xh,
                                               unsigned short* __restrict__ Xl) {
    const size_t i = ((size_t)blockIdx.x * 256 + threadIdx.x) * 8;
    float4 a = *(const float4*)(X + i);
    float4 b = *(const float4*)(X + i + 4);
    ushort4 h0, h1, l0, l1;
    float v, hf;
    v = a.x; h0.x = f2b(v); hf = b2f(h0.x); l0.x = f2b(v - hf);
    v = a.y; h0.y = f2b(v); hf = b2f(h0.y); l0.y = f2b(v - hf);
    v = a.z; h0.z = f2b(v); hf = b2f(h0.z); l0.z = f2b(v - hf);
    v = a.w; h0.w = f2b(v); hf = b2f(h0.w); l0.w = f2b(v - hf);
    v = b.x; h1.x = f2b(v); hf = b2f(h1.x); l1.x = f2b(v - hf);
    v = b.y; h1.y = f2b(v); hf = b2f(h1.y); l1.y = f2b(v - hf);
    v = b.z; h1.z = f2b(v); hf = b2f(h1.z); l1.z = f2b(v - hf);
    v = b.w; h1.w = f2b(v); hf = b2f(h1.w); l1.w = f2b(v - hf);
    *(ushort4*)(Xh + i) = h0; *(ushort4*)(Xh + i + 4) = h1;
    *(ushort4*)(Xl + i) = l0; *(ushort4*)(Xl + i + 4) = l1;
}

// ------------------------------------- W [k][n] -> Wt hi/lo [n][k] (bf16 split, transpose)
__global__ __launch_bounds__(256) void split_wT(const float* __restrict__ W,
                                                unsigned short* __restrict__ Th,
                                                unsigned short* __restrict__ Tl) {
    const int k0 = blockIdx.y * 64, n0 = blockIdx.x * 64;
    __shared__ float tile[64][65];
#pragma unroll
    for (int q = 0; q < 16; q++) {
        int idx = q * 256 + threadIdx.x;
        int r = idx >> 6, c = idx & 63;
        tile[r][c] = W[(size_t)(k0 + r) * HH + n0 + c];
    }
    __syncthreads();
#pragma unroll
    for (int q = 0; q < 16; q++) {
        int idx = q * 256 + threadIdx.x;
        int r = idx >> 6, c = idx & 63;
        float v = tile[c][r];
        unsigned short h = f2b(v);
        Th[(size_t)(n0 + r) * HH + k0 + c] = h;
        Tl[(size_t)(n0 + r) * HH + k0 + c] = f2b(v - b2f(h));
    }
}

// ---- helper macros for the shared split-bf16 body ----
#define STG_A(mh, kt, buf) do { \
        const size_t o_ = aOff + (size_t)(mh) * 64 * HH + (size_t)(kt) * 32; \
        async_load16(A_h + o_, (char*)lds + ((buf) * 32768 + (mh) * 4096) * 2 + wt16); \
        async_load16(A_l + o_, (char*)lds + ((buf) * 32768 + 8192 + (mh) * 4096) * 2 + wt16); \
    } while (0)
#define STG_B(nh, kt, buf) do { \
        const size_t o_ = bOff + (size_t)(nh) * 32 * HH + (size_t)(kt) * 32; \
        async_load16(B_h + o_, (char*)lds + ((buf) * 32768 + 16384 + (nh) * 4096) * 2 + wt16); \
        async_load16(B_l + o_, (char*)lds + ((buf) * 32768 + 24576 + (nh) * 4096) * 2 + wt16); \
    } while (0)
#define RD_A_H(mh, buf) do { \
        const int s0_ = (buf) * 32768 + ((mh) * 128 + wy * 64 + m16) * 32 + cs * 8; \
        _Pragma("unroll") for (int mi = 0; mi < 4; ++mi) \
            a_h[mi] = *(const bf16x8*)&lds[s0_ + mi * 512]; \
    } while (0)
#define RD_A_L(mh, buf) do { \
        const int s0_ = (buf) * 32768 + ((mh) * 128 + wy * 64 + m16) * 32 + cs * 8; \
        _Pragma("unroll") for (int mi = 0; mi < 4; ++mi) \
            a_l[mi] = *(const bf16x8*)&lds[8192 + s0_ + mi * 512]; \
    } while (0)
#define RD_B_H(nh, buf) do { \
        const int s0_ = (buf) * 32768 + ((nh) * 128 + wx * 32 + m16) * 32 + cs * 8; \
        _Pragma("unroll") for (int nj = 0; nj < 2; ++nj) \
            b_h[nh][nj] = *(const bf16x8*)&lds[16384 + s0_ + nj * 512]; \
    } while (0)
#define RD_B_L(nh, buf) do { \
        const int s0_ = (buf) * 32768 + ((nh) * 128 + wx * 32 + m16) * 32 + cs * 8; \
        _Pragma("unroll") for (int nj = 0; nj < 2; ++nj) \
            b_l[nh][nj] = *(const bf16x8*)&lds[24576 + s0_ + nj * 512]; \
    } while (0)
// pass-major MFMA passes (per-acc order hh -> hl -> lh preserved = bit-identical)
#define PASS_HH(mh) \
        _Pragma("unroll") for (int mi = 0; mi < 4; ++mi) \
        _Pragma("unroll") for (int nh = 0; nh < 2; ++nh) \
        _Pragma("unroll") for (int nj = 0; nj < 2; ++nj) \
            acc[mh][mi][nh][nj] = __builtin_amdgcn_mfma_f32_16x16x32_bf16(a_h[mi], b_h[nh][nj], acc[mh][mi][nh][nj], 0, 0, 0);
#define PASS_HL(mh) \
        _Pragma("unroll") for (int mi = 0; mi < 4; ++mi) \
        _Pragma("unroll") for (int nh = 0; nh < 2; ++nh) \
        _Pragma("unroll") for (int nj = 0; nj < 2; ++nj) \
            acc[mh][mi][nh][nj] = __builtin_amdgcn_mfma_f32_16x16x32_bf16(a_h[mi], b_l[nh][nj], acc[mh][mi][nh][nj], 0, 0, 0);
#define PASS_LH(mh) \
        _Pragma("unroll") for (int mi = 0; mi < 4; ++mi) \
        _Pragma("unroll") for (int nh = 0; nh < 2; ++nh) \
        _Pragma("unroll") for (int nj = 0; nj < 2; ++nj) \
            acc[mh][mi][nh][nj] = __builtin_amdgcn_mfma_f32_16x16x32_bf16(a_l[mi], b_h[nh][nj], acc[mh][mi][nh][nj], 0, 0, 0);

// Shared 2-phase split-bf16 GEMM body (NT, 256² tile, BK=32, 2M x 4N waves).
#define SPLIT3_2PH_BODY(A_h, A_l, B_h, B_l)                                         \
    __shared__ __align__(16) unsigned short lds[65536];                             \
    const int tid = threadIdx.x;                                                    \
    const int wave = tid >> 6, lane = tid & 63;                                     \
    const int m16 = lane & 15, quad = lane >> 4;                                    \
    const int wy = wave >> 2, wx = wave & 3;                                        \
    const int rP = tid >> 2;                                                        \
    const int kq = (tid & 3) ^ ((rP >> 1) & 3);                                     \
    const int cs = quad ^ ((m16 >> 1) & 3);                                         \
    const int wt16 = wave * 1024;                                                   \
    const int rowA_off = (rP & 63) + ((rP >> 6) << 7);                              \
    const int rowB_off = ((rP >> 5) << 6) + (rP & 31);                              \
    const size_t aOff = (size_t)(i0 + rowA_off) * HH + kq * 8;                      \
    const size_t bOff = (size_t)(j0 + rowB_off) * HH + kq * 8;                      \
    f32x4 acc[2][4][2][2] = {};                                                     \
    bf16x8 a_h[4], a_l[4], b_h[2][2], b_l[2][2];                                    \
    STG_A(0, 0, 0); STG_A(1, 0, 0);                                                 \
    STG_B(0, 0, 0); STG_B(1, 0, 0);                                                 \
    STG_B(0, 1, 1); STG_B(1, 1, 1);                                                 \
    asm volatile("s_waitcnt vmcnt(4)" ::: "memory");                                \
    __builtin_amdgcn_s_barrier();                                                   \
    RD_A_H(0, 0); RD_A_L(0, 0);                                                     \
    RD_B_H(0, 0); RD_B_L(0, 0); RD_B_H(1, 0); RD_B_L(1, 0);                         \
    for (int kt = 0; kt < 32; ++kt) {                                               \
        const int bufc = kt & 1, bufn = bufc ^ 1;                                   \
        const int ktA = kt < 31 ? kt + 1 : 31;                                      \
        const int ktB = kt < 30 ? kt + 2 : 31;                                      \
        /* ---- ph0 (mh0) */                                                        \
        STG_A(0, ktA, bufn);                                                        \
        STG_A(1, ktA, bufn);                                                        \
        asm volatile("s_waitcnt vmcnt(8)" ::: "memory");                            \
        __builtin_amdgcn_s_barrier();                                               \
        __builtin_amdgcn_sched_barrier(0);                                          \
        __builtin_amdgcn_s_setprio(1);                                              \
        PASS_HH(0)                                                                  \
        PASS_HL(0)                                                                  \
        __builtin_amdgcn_sched_barrier(0);                                          \
        RD_A_H(1, bufc);                                                            \
        __builtin_amdgcn_sched_barrier(0);                                          \
        PASS_LH(0)                                                                  \
        __builtin_amdgcn_s_setprio(0);                                              \
        __builtin_amdgcn_sched_barrier(0);                                          \
        RD_A_L(1, bufc);                                                            \
        __builtin_amdgcn_s_barrier();                                               \
        /* ---- ph1 (mh1) */                                                        \
        STG_B(0, ktB, bufc);                                                        \
        STG_B(1, ktB, bufc);                                                        \
        asm volatile("s_waitcnt vmcnt(4)" ::: "memory");                            \
        __builtin_amdgcn_s_barrier();                                               \
        __builtin_amdgcn_sched_barrier(0);                                          \
        __builtin_amdgcn_s_setprio(1);                                              \
        PASS_HH(1)                                                                  \
        PASS_HL(1)                                                                  \
        __builtin_amdgcn_sched_barrier(0);                                          \
        RD_B_L(0, bufn); RD_B_L(1, bufn); RD_A_H(0, bufn);                          \
        __builtin_amdgcn_sched_barrier(0);                                          \
        PASS_LH(1)                                                                  \
        __builtin_amdgcn_s_setprio(0);                                              \
        __builtin_amdgcn_sched_barrier(0);                                          \
        RD_B_H(0, bufn); RD_B_H(1, bufn); RD_A_L(0, bufn);                          \
        __builtin_amdgcn_s_barrier();                                               \
    }

// ---------------- xw = x @ Wt^T (NT), 3-pass split-bf16, 2-phase 256² BK=32, bf16 hi/lo out
__global__ __launch_bounds__(512, 2) void gemm_xw3_8p(const unsigned short* __restrict__ Ah,
                                                      const unsigned short* __restrict__ Al,
                                                      const unsigned short* __restrict__ Bh,
                                                      const unsigned short* __restrict__ Bl,
                                                      unsigned short* __restrict__ Ch,
                                                      unsigned short* __restrict__ Cl) {
    int tx, ty, b;
    swz_tile(gridDim.x, gridDim.y, tx, ty, b);
    const int i0 = ty * 256, j0 = tx * 256;
    const unsigned short* A_h = Ah + (size_t)b * SS * HH;
    const unsigned short* A_l = Al + (size_t)b * SS * HH;
    const unsigned short* B_h = Bh;   // Wt: no batch offset
    const unsigned short* B_l = Bl;

    SPLIT3_2PH_BODY(A_h, A_l, B_h, B_l)

    unsigned short* ChB = Ch + (size_t)b * SS * HH;
    unsigned short* ClB = Cl + (size_t)b * SS * HH;
#pragma unroll
    for (int mh = 0; mh < 2; ++mh)
#pragma unroll
        for (int mi = 0; mi < 4; ++mi)
#pragma unroll
            for (int nh = 0; nh < 2; ++nh)
#pragma unroll
                for (int nj = 0; nj < 2; ++nj) {
                    const int row = i0 + wy * 128 + mh * 64 + mi * 16 + quad * 4;
                    const int col = j0 + wx * 64 + nh * 32 + nj * 16 + m16;
#pragma unroll
                    for (int reg = 0; reg < 4; ++reg) {
                        float v = acc[mh][mi][nh][nj][reg];
                        unsigned short h = f2b(v);
                        ChB[(size_t)(row + reg) * HH + col] = h;
                        ClB[(size_t)(row + reg) * HH + col] = f2b(v - b2f(h));
                    }
                }
}

// ---------------- scores = xw @ x^T (NT), 3-pass split-bf16 MFMA, fp32 out
__global__ __launch_bounds__(512, 2) void gemm_sc3_8p(const unsigned short* __restrict__ Ah,
                                                      const unsigned short* __restrict__ Al,
                                                      const unsigned short* __restrict__ Bh,
                                                      const unsigned short* __restrict__ Bl,
                                                      float* __restrict__ SC) {
    int tx, ty, b;
    swz_tile(gridDim.x, gridDim.y, tx, ty, b);
    const int i0 = ty * 256, j0 = tx * 256;
    const unsigned short* A_h = Ah + (size_t)b * SS * HH;
    const unsigned short* A_l = Al + (size_t)b * SS * HH;
    const unsigned short* B_h = Bh + (size_t)b * SS * HH;
    const unsigned short* B_l = Bl + (size_t)b * SS * HH;

    SPLIT3_2PH_BODY(A_h, A_l, B_h, B_l)

    float* Cb = SC + (size_t)b * SS * SS;
#pragma unroll
    for (int mh = 0; mh < 2; ++mh)
#pragma unroll
        for (int mi = 0; mi < 4; ++mi)
#pragma unroll
            for (int nh = 0; nh < 2; ++nh)
#pragma unroll
                for (int nj = 0; nj < 2; ++nj) {
                    const int row = i0 + wy * 128 + mh * 64 + mi * 16 + quad * 4;
                    const int col = j0 + wx * 64 + nh * 32 + nj * 16 + m16;
#pragma unroll
                    for (int reg = 0; reg < 4; ++reg)
                        Cb[(size_t)(row + reg) * SS + col] = acc[mh][mi][nh][nj][reg];
                }
}

#undef STG_A
#undef STG_B
#undef RD_A_H
#undef RD_A_L
#undef RD_B_H
#undef RD_B_L
#undef PASS_HH
#undef PASS_HL
#undef PASS_LH
#undef SPLIT3_2PH_BODY

// ------------- softmax in place (fp32, nontemporal out) + bf16 copy; 2 rows/block
__global__ __launch_bounds__(512) void softmax_rows(float* __restrict__ P,
                                                    unsigned short* __restrict__ Pb) {
    const int tid = threadIdx.x;
    const int half = tid >> 8, t = tid & 255;
    const size_t row = (size_t)blockIdx.x * 2 + half;
    float4* p4 = (float4*)(P + row * SS);
    float4 v0 = p4[t], v1 = p4[t + 256];
    float m = fmaxf(fmaxf(fmaxf(v0.x, v0.y), fmaxf(v0.z, v0.w)),
                    fmaxf(fmaxf(v1.x, v1.y), fmaxf(v1.z, v1.w)));
#pragma unroll
    for (int off = 32; off; off >>= 1) m = fmaxf(m, __shfl_xor(m, off));
    __shared__ float red[8];
    const int wid = tid >> 6, lane = tid & 63;
    const int rb = half << 2;
    if (lane == 0) red[wid] = m;
    __syncthreads();
    m = fmaxf(fmaxf(red[rb], red[rb + 1]), fmaxf(red[rb + 2], red[rb + 3]));
    v0.x = __expf(v0.x - m); v0.y = __expf(v0.y - m);
    v0.z = __expf(v0.z - m); v0.w = __expf(v0.w - m);
    v1.x = __expf(v1.x - m); v1.y = __expf(v1.y - m);
    v1.z = __expf(v1.z - m); v1.w = __expf(v1.w - m);
    float s = v0.x + v0.y + v0.z + v0.w + v1.x + v1.y + v1.z + v1.w;
#pragma unroll
    for (int off = 32; off; off >>= 1) s += __shfl_xor(s, off);
    __syncthreads();
    if (lane == 0) red[wid] = s;
    __syncthreads();
    s = red[rb] + red[rb + 1] + red[rb + 2] + red[rb + 3];
    const float inv = 1.0f / s;
    v0.x *= inv; v0.y *= inv; v0.z *= inv; v0.w *= inv;
    v1.x *= inv; v1.y *= inv; v1.z *= inv; v1.w *= inv;
    __builtin_nontemporal_store(*(f32x4*)&v0, (f32x4*)(p4 + t));
    __builtin_nontemporal_store(*(f32x4*)&v1, (f32x4*)(p4 + t + 256));
    ushort4* b4 = (ushort4*)(Pb + row * SS);
    ushort4 u0 = { f2b(v0.x), f2b(v0.y), f2b(v0.z), f2b(v0.w) };
    ushort4 u1 = { f2b(v1.x), f2b(v1.y), f2b(v1.z), f2b(v1.w) };
    b4[t] = u0;
    b4[t + 256] = u1;
}

// --------------------------------- x [B,S,H] fp32 -> xT [B,H,S] bf16 (for NT ctx GEMM)
__global__ __launch_bounds__(256) void transpose_cvt(const float* __restrict__ X,
                                                     unsigned short* __restrict__ XT) {
    const int b = blockIdx.z;
    const int t0 = blockIdx.y * 64;
    const int h0 = blockIdx.x * 64;
    __shared__ float tile[64][65];
    const float* Xb = X + (size_t)b * SS * HH;
    unsigned short* Tb = XT + (size_t)b * HH * SS;
#pragma unroll
    for (int q = 0; q < 16; q++) {
        int idx = q * 256 + threadIdx.x;
        int r = idx >> 6, c = idx & 63;
        tile[r][c] = Xb[(size_t)(t0 + r) * HH + h0 + c];
    }
    __syncthreads();
#pragma unroll
    for (int q = 0; q < 16; q++) {
        int idx = q * 256 + threadIdx.x;
        int r = idx >> 6, c = idx & 63;
        Tb[(size_t)(h0 + r) * SS + t0 + c] = f2b(tile[c][r]);
    }
}

// ----------------- ctx = attn @ x (NT bf16 MFMA), 2-phase 256² tile, BK=64, 1-pass
__global__ __launch_bounds__(512, 2) void gemm_ctx_8p(const unsigned short* __restrict__ Ab,
                                                      const unsigned short* __restrict__ Bt,
                                                      float* __restrict__ C) {
    int tx, ty, b;
    swz_tile(gridDim.x, gridDim.y, tx, ty, b);
    const int i0 = ty * 256, n0 = tx * 256;
    const unsigned short* A = Ab + (size_t)b * SS * SS;
    const unsigned short* B = Bt + (size_t)b * HH * SS;

    __shared__ __align__(16) unsigned short lds[65536];   // 128 KB

    const int tid = threadIdx.x;
    const int wave = tid >> 6, lane = tid & 63;
    const int m16 = lane & 15, quad = lane >> 4;
    const int m7 = m16 & 7;
    const int wy = wave >> 2, wx = wave & 3;
    const int rA8 = tid >> 3;
    const int c8 = (tid & 7) ^ (rA8 & 7);
    const int wt16 = wave * 1024;
    const int sl0 = (quad ^ m7) * 8;          // ushort offset, ks=0 slot
    const int sl1 = ((quad + 4) ^ m7) * 8;    // ks=1 slot

    const size_t aSrc = (size_t)(i0 + rA8) * SS + c8 * 8;
    const size_t bSrc = (size_t)(n0 + ((rA8 >> 5) << 6) + (rA8 & 31)) * SS + c8 * 8;

    f32x4 acc[2][4][2][2] = {};               // [mh][mi][nh][nj]
    bf16x8 a[4][2], bb[2][2][2];              // a[mi][ks], bb[nh][nj][ks]

#define CSTG_A(mh, h, kt, buf) \
    async_load16(A + aSrc + (size_t)((mh) * 64 + (h) * 128) * SS + (size_t)(kt) * 64, \
                 (char*)lds + (buf) * 65536 + (mh) * 16384 + (h) * 8192 + wt16)
#define CSTG_B(nh, h, kt, buf) \
    async_load16(B + bSrc + (size_t)((h) * 128 + (nh) * 32) * SS + (size_t)(kt) * 64, \
                 (char*)lds + (buf) * 65536 + 32768 + (nh) * 16384 + (h) * 8192 + wt16)
#define CRD_A_S0(mh, buf) do { \
        const int r0_ = (buf) * 32768 + ((mh) * 128 + wy * 64 + m16) * 64; \
        _Pragma("unroll") for (int mi = 0; mi < 4; ++mi) \
            a[mi][0] = *(const bf16x8*)&lds[r0_ + mi * 1024 + sl0]; \
    } while (0)
#define CRD_A_S1(mh, buf) do { \
        const int r0_ = (buf) * 32768 + ((mh) * 128 + wy * 64 + m16) * 64; \
        _Pragma("unroll") for (int mi = 0; mi < 4; ++mi) \
            a[mi][1] = *(const bf16x8*)&lds[r0_ + mi * 1024 + sl1]; \
    } while (0)
#define CRD_B_S0(nh, buf) do { \
        const int r0_ = (buf) * 32768 + 16384 + (nh) * 8192 + (wx * 32 + m16) * 64; \
        _Pragma("unroll") for (int nj = 0; nj < 2; ++nj) \
            bb[nh][nj][0] = *(const bf16x8*)&lds[r0_ + nj * 1024 + sl0]; \
    } while (0)
#define CRD_B_S1(nh, buf) do { \
        const int r0_ = (buf) * 32768 + 16384 + (nh) * 8192 + (wx * 32 + m16) * 64; \
        _Pragma("unroll") for (int nj = 0; nj < 2; ++nj) \
            bb[nh][nj][1] = *(const bf16x8*)&lds[r0_ + nj * 1024 + sl1]; \
    } while (0)
#define CPASS0(mh) \
        _Pragma("unroll") for (int mi = 0; mi < 4; ++mi) \
        _Pragma("unroll") for (int nh = 0; nh < 2; ++nh) \
        _Pragma("unroll") for (int nj = 0; nj < 2; ++nj) \
            acc[mh][mi][nh][nj] = __builtin_amdgcn_mfma_f32_16x16x32_bf16(a[mi][0], bb[nh][nj][0], acc[mh][mi][nh][nj], 0, 0, 0);
#define CPASS1(mh) \
        _Pragma("unroll") for (int mi = 0; mi < 4; ++mi) \
        _Pragma("unroll") for (int nh = 0; nh < 2; ++nh) \
        _Pragma("unroll") for (int nj = 0; nj < 2; ++nj) \
            acc[mh][mi][nh][nj] = __builtin_amdgcn_mfma_f32_16x16x32_bf16(a[mi][1], bb[nh][nj][1], acc[mh][mi][nh][nj], 0, 0, 0);

    CSTG_A(0, 0, 0, 0); CSTG_A(0, 1, 0, 0);
    CSTG_A(1, 0, 0, 0); CSTG_A(1, 1, 0, 0);
    CSTG_B(0, 0, 0, 0); CSTG_B(0, 1, 0, 0);
    CSTG_B(1, 0, 0, 0); CSTG_B(1, 1, 0, 0);
    CSTG_B(0, 0, 1, 1); CSTG_B(0, 1, 1, 1);
    CSTG_B(1, 0, 1, 1); CSTG_B(1, 1, 1, 1);
    asm volatile("s_waitcnt vmcnt(4)" ::: "memory");
    __builtin_amdgcn_s_barrier();
    CRD_A_S0(0, 0); CRD_A_S1(0, 0);
    CRD_B_S0(0, 0); CRD_B_S1(0, 0); CRD_B_S0(1, 0); CRD_B_S1(1, 0);

    for (int kt = 0; kt < 32; ++kt) {
        const int bufc = kt & 1, bufn = bufc ^ 1;
        const int ktA = kt < 31 ? kt + 1 : 31;
        const int ktB = kt < 30 ? kt + 2 : 31;
        // ---- ph0 (mh0)
        CSTG_A(0, 0, ktA, bufn); CSTG_A(0, 1, ktA, bufn);
        CSTG_A(1, 0, ktA, bufn); CSTG_A(1, 1, ktA, bufn);
        asm volatile("s_waitcnt vmcnt(8)" ::: "memory");
        __builtin_amdgcn_s_barrier();
        __builtin_amdgcn_sched_barrier(0);
        __builtin_amdgcn_s_setprio(1);
        CPASS0(0)
        __builtin_amdgcn_sched_barrier(0);
        CRD_A_S0(1, bufc);
        __builtin_amdgcn_sched_barrier(0);
        CPASS1(0)
        __builtin_amdgcn_s_setprio(0);
        __builtin_amdgcn_sched_barrier(0);
        CRD_A_S1(1, bufc);
        __builtin_amdgcn_s_barrier();
        // ---- ph1 (mh1)
        CSTG_B(0, 0, ktB, bufc); CSTG_B(0, 1, ktB, bufc);
        CSTG_B(1, 0, ktB, bufc); CSTG_B(1, 1, ktB, bufc);
        asm volatile("s_waitcnt vmcnt(4)" ::: "memory");
        __builtin_amdgcn_s_barrier();
        __builtin_amdgcn_sched_barrier(0);
        __builtin_amdgcn_s_setprio(1);
        CPASS0(1)
        __builtin_amdgcn_sched_barrier(0);
        CRD_B_S0(0, bufn); CRD_B_S0(1, bufn); CRD_A_S0(0, bufn);
        __builtin_amdgcn_sched_barrier(0);
        CPASS1(1)
        __builtin_amdgcn_s_setprio(0);
        __builtin_amdgcn_sched_barrier(0);
        CRD_B_S1(0, bufn); CRD_B_S1(1, bufn); CRD_A_S1(0, bufn);
        __builtin_amdgcn_s_barrier();
    }

    float* Cb = C + (size_t)b * SS * HH;
#pragma unroll
    for (int mh = 0; mh < 2; ++mh)
#pragma unroll
        for (int mi = 0; mi < 4; ++mi)
#pragma unroll
            for (int nh = 0; nh < 2; ++nh)
#pragma unroll
                for (int nj = 0; nj < 2; ++nj) {
                    const int row = i0 + wy * 128 + mh * 64 + mi * 16 + quad * 4;
                    const int col = n0 + wx * 64 + nh * 32 + nj * 16 + m16;
#pragma unroll
                    for (int reg = 0; reg < 4; ++reg)
                        __builtin_nontemporal_store(acc[mh][mi][nh][nj][reg],
                                                    &Cb[(size_t)(row + reg) * HH + col]);
                }
#undef CSTG_A
#undef CSTG_B
#undef CRD_A_S0
#undef CRD_A_S1
#undef CRD_B_S0
#undef CRD_B_S1
#undef CPASS0
#undef CPASS1
}

extern "C" void kernel_launch(void* const* d_in, const int* in_sizes, int n_in,
                              void* d_out, int out_size, void* d_ws, size_t ws_size,
                              hipStream_t stream) {
    const float* X = (const float*)d_in[0];   // [8,2048,1024]
    const float* W = (const float*)d_in[1];   // [1024,1024]
    float* ctx  = (float*)d_out;                            // [8,2048,1024]
    float* attn = ctx + (size_t)BB * SS * HH;               // [8,2048,2048]

    char* ws = (char*)d_ws;
    unsigned short* x_hi  = (unsigned short*)ws;                         // [0,32M)
    unsigned short* x_lo  = (unsigned short*)(ws + ((size_t)32 << 20));  // [32,64M)
    unsigned short* wt_hi = (unsigned short*)(ws + ((size_t)64 << 20));  // [64,66M)
    unsigned short* wt_lo = (unsigned short*)(ws + ((size_t)66 << 20));  // [66,68M)
    unsigned short* xT     = x_hi;                                       // after scores
    unsigned short* attn_b = x_lo;                                       // after scores

    unsigned short* xw_hi = (unsigned short*)d_out;   // dead ctx region until final GEMM
    unsigned short* xw_lo = xw_hi + (size_t)BB * SS * HH;

    dim3 blk(256);
    split_x <<<dim3(BB * SS * HH / (8 * 256)), blk, 0, stream>>>(X, x_hi, x_lo);
    split_wT<<<dim3(HH / 64, HH / 64), blk, 0, stream>>>(W, wt_hi, wt_lo);
    gemm_xw3_8p<<<dim3(HH / 256, SS / 256, BB), dim3(512), 0, stream>>>(x_hi, x_lo, wt_hi, wt_lo, xw_hi, xw_lo);
    gemm_sc3_8p<<<dim3(SS / 256, SS / 256, BB), dim3(512), 0, stream>>>(xw_hi, xw_lo, x_hi, x_lo, attn);
    transpose_cvt<<<dim3(HH / 64, SS / 64, BB), blk, 0, stream>>>(X, xT);
    softmax_rows <<<dim3(BB * SS / 2), dim3(512), 0, stream>>>(attn, attn_b);
    gemm_ctx_8p<<<dim3(HH / 256, SS / 256, BB), dim3(512), 0, stream>>>(attn_b, xT, ctx);
}